// Round 9
// baseline (144.879 us; speedup 1.0000x reference)
//
#include <hip/hip_runtime.h>

// SigLoss: signature kernel PDE, loss = mean_a( K(X,X) + K(Y,Y) - 2 K(X,Y) ).
// A=256, L=256, D=32.
// R9: two staggered waves per (pair,a) problem, column-split (wave0: cols
// 0..127, wave1: 128..255 running LAG=8 rows behind; barrier every 8 rows,
// 33 total). R8's running-dot form (no LDS dX, U rows via uniform s_load):
// inc[r][j] = U[r+1]·dY_j - U[r]·dY_j. Per-lane state: 2 dY columns = 64
// floats + ~30 working ≈ 95 VGPR — UNDER the ~132 grant R3-R8 demonstrated,
// so dY is finally resident and the scheduler has spare regs to pipeline
// next-row dots under the serial scan chain. Cross-wave handoff is one float
// per row: T0(r) (wave0's row total), via a 16-slot LDS ring.

#define NROW 255
#define ND 32
#define LAG 8

#define DPP_ADD(v, ctrl, rmask)                                               \
    ((v) + __int_as_float(__builtin_amdgcn_update_dpp(                        \
               0, __float_as_int(v), (ctrl), (rmask), 0xF, true)))

__global__ __launch_bounds__(128)
__attribute__((amdgpu_waves_per_eu(1)))
void sig_pde(const float* __restrict__ X,
             const float* __restrict__ Y,
             float* __restrict__ partial) {
    const int bid = blockIdx.x;
    const int p = bid >> 8;          // 0=xx, 1=yy, 2=xy
    const int a = bid & 255;
    const float* __restrict__ U = (p == 1) ? Y : X;   // rows (i)
    const float* __restrict__ V = (p == 0) ? X : Y;   // cols (j)
    U += (size_t)a * 256 * ND;
    V += (size_t)a * 256 * ND;
    const int tid = threadIdx.x;
    const int wid = tid >> 6;
    const int lane = tid & 63;
    const bool w0 = (wid == 0);

    __shared__ float t0buf[16];      // T0 ring, wave0 -> wave1 (64 B LDS)

    // dY diffs for 2 columns per lane: j0 = wid*128 + 2*lane, j0+1.
    const int j0 = (wid << 7) + 2 * lane;
    const float4* V4 = (const float4*)V;
    float dy0[ND], dy1[ND];
    {
        const int r2 = (j0 + 2 < 256) ? j0 + 2 : 255;  // wave1 lane63 -> dy1=0
#pragma unroll
        for (int c = 0; c < 8; ++c) {
            float4 v0 = V4[j0 * 8 + c];
            float4 v1 = V4[(j0 + 1) * 8 + c];
            float4 v2 = V4[r2 * 8 + c];
            dy0[4 * c + 0] = v1.x - v0.x;  dy1[4 * c + 0] = v2.x - v1.x;
            dy0[4 * c + 1] = v1.y - v0.y;  dy1[4 * c + 1] = v2.y - v1.y;
            dy0[4 * c + 2] = v1.z - v0.z;  dy1[4 * c + 2] = v2.z - v1.z;
            dy0[4 * c + 3] = v1.w - v0.w;  dy1[4 * c + 3] = v2.w - v1.w;
        }
    }

    // Uniform U row -> SGPRs (s_load); double-buffered across the row loop.
    float urA[ND], urB[ND];
    auto loadU = [&](int row, float (&dst)[ND]) {
        const float* __restrict__ Ur = U + row * ND;
#pragma unroll
        for (int d = 0; d < ND; ++d) dst[d] = Ur[d];
    };

    // n[s] = dot(ur, dy[s]): 4 independent FMA chains
    float n0, n1;
    auto dots = [&](const float (&ur)[ND]) {
        float a0 = 0.f, b0 = 0.f, a1 = 0.f, b1 = 0.f;
#pragma unroll
        for (int d = 0; d < ND; d += 2) {
            a0 = fmaf(ur[d], dy0[d], a0);
            b0 = fmaf(ur[d + 1], dy0[d + 1], b0);
            a1 = fmaf(ur[d], dy1[d], a1);
            b1 = fmaf(ur[d + 1], dy1[d + 1], b1);
        }
        n0 = a0 + b0; n1 = a1 + b1;
    };

    // Running dot + 1: gp1[s] = U[r]·dy[s] + 1, so inc-1 = n - gp1.
    loadU(0, urA);
    dots(urA);
    float gp10 = n0 + 1.0f, gp11 = n1 + 1.0f;

    // K row state: kp0/kp1 = K[r][j0], K[r][j0+1]; row 0 = ones.
    float kp0 = 1.0f, kp1 = 1.0f;
    float t0p = 0.0f;  // wave0 lane63: T0(r-1); row0 boundary K[0][128]=1+0

    auto phase_row = [&](const float (&ur)[ND], int r) {
        float t0row = 0.0f;
        if (!w0) t0row = t0buf[r & 15];     // prefetch early (LDS broadcast)
        dots(ur);                            // n = U[r+1]·dy
        float m0 = n0 - gp10, m1 = n1 - gp11;   // inc - 1
        gp10 = n0 + 1.0f; gp11 = n1 + 1.0f;

        // c[j] = K[r][j+1] + K[r][j]*(inc-1); next lane's kp0 via wave_shl:1
        float kn = __int_as_float(__builtin_amdgcn_update_dpp(
            0, __float_as_int(kp0), 0x130 /*wave_shl:1*/, 0xF, 0xF, true));
        float c0 = fmaf(kp0, m0, kp1);
        float c1;
        if (w0) {
            // lane63: prev[128] = 1 + T0(r-1) (own previous row total)
            c1 = (lane == 63) ? fmaf(kp1, m1, 1.0f + t0p) : fmaf(kp1, m1, kn);
        } else {
            c1 = (lane == 63) ? 0.0f : fmaf(kp1, m1, kn);  // c[255] absent
        }

        float T = c0 + c1;
        float S = T;
        S = DPP_ADD(S, 0x111, 0xF);  // row_shr:1
        S = DPP_ADD(S, 0x112, 0xF);  // row_shr:2
        S = DPP_ADD(S, 0x114, 0xF);  // row_shr:4
        S = DPP_ADD(S, 0x118, 0xF);  // row_shr:8
        S = DPP_ADD(S, 0x142, 0xA);  // row_bcast:15 -> rows 1,3
        S = DPP_ADD(S, 0x143, 0xC);  // row_bcast:31 -> rows 2,3
        float E = S - T;             // exclusive: sum of lower lanes' totals

        if (w0) {
            if (lane == 63) {
                t0buf[r & 15] = S;   // T0(r) = total over cols 0..127
                t0p = S;
            }
            kp0 = 1.0f + E;
            kp1 = 1.0f + E + c0;
        } else {
            kp0 = 1.0f + t0row + E;  // K[r+1][128+2*lane]
            kp1 = 1.0f + t0row + E + c0;
        }
    };

    // Staggered phase loop: wave0 does rows [ph*8, ph*8+8); wave1 the block
    // before. Barrier between blocks orders the T0 ring handoff (16 slots =
    // 2 blocks -> writer and reader always in disjoint halves).
    loadU(1, urA);                    // ur for row 0 (= U row 1)
    int parity = 0;
    const int roff = w0 ? 0 : LAG;
    for (int ph = 0; ph < 33; ++ph) {
#pragma unroll
        for (int k = 0; k < LAG; ++k) {
            const int r = ph * LAG + k - roff;
            if (r >= 0 && r < NROW) {
                const int rn = (r + 2 < 256) ? r + 2 : 255;  // next ur row
                if (parity == 0) { loadU(rn, urB); phase_row(urA, r); }
                else             { loadU(rn, urA); phase_row(urB, r); }
                parity ^= 1;
            }
        }
        __syncthreads();
    }

    if (!w0 && lane == 63) {
        // kp1 = K[255][255]
        partial[bid] = (p == 2 ? -2.0f : 1.0f) * kp1;
    }
}

__global__ __launch_bounds__(256) void sig_reduce(const float* __restrict__ partial,
                                                  float* __restrict__ out) {
    const int t = threadIdx.x;
    float v = partial[t] + partial[t + 256] + partial[t + 512];
#pragma unroll
    for (int ofs = 32; ofs > 0; ofs >>= 1) v += __shfl_down(v, ofs);
    __shared__ float ws[4];
    if ((t & 63) == 0) ws[t >> 6] = v;
    __syncthreads();
    if (t == 0) out[0] = (ws[0] + ws[1] + ws[2] + ws[3]) * (1.0f / 256.0f);
}

extern "C" void kernel_launch(void* const* d_in, const int* in_sizes, int n_in,
                              void* d_out, int out_size, void* d_ws, size_t ws_size,
                              hipStream_t stream) {
    const float* X = (const float*)d_in[0];
    const float* Y = (const float*)d_in[1];
    float* partial = (float*)d_ws;       // 768 floats
    sig_pde<<<dim3(768), dim3(128), 0, stream>>>(X, Y, partial);
    sig_reduce<<<dim3(1), dim3(256), 0, stream>>>(partial, (float*)d_out);
}

// Round 11
// 57.230 us; speedup vs baseline: 2.5315x; 2.5315x over previous
//
#include <hip/hip_runtime.h>

// SigLoss: signature kernel PDE, loss = mean_a( K(X,X) + K(Y,Y) - 2 K(X,Y) ).
// A=256, L=256, D=32. One 64-lane wave per (pair,a) problem.
// R11: inc = dX·dY^T via MFMA f32_16x16x32_f16 with two-term f16 split
// (hi + lo*2^-11; 3 products; rel err ~2^-22 — R10 proved single f16's
// 2^-12 is 6x too coarse). dY hi/lo frags staged once in LDS (ends the
// VGPR-residency war of R3-R9). inc round-trips a 16x260 LDS buffer
// (pad 260 -> 2-way-free b32 writes, aligned b128 scan reads). Single
// wave: scan(block b-1) precedes writes(block b) in program order, so a
// single inc buffer is race-free, zero barriers. Scan = R3's verified
// DPP core, consuming inc-1 directly (the -1 folded into MFMA C-init).
// LDS 49.4 KB -> 3 blocks/CU -> all 768 waves resident.

typedef _Float16 half8 __attribute__((ext_vector_type(8)));
typedef float f32x4_t __attribute__((ext_vector_type(4)));
typedef unsigned int u32x4 __attribute__((ext_vector_type(4)));

#define DPP_ADD(v, ctrl, rmask)                                               \
    ((v) + __int_as_float(__builtin_amdgcn_update_dpp(                        \
               0, __float_as_int(v), (ctrl), (rmask), 0xF, true)))

#define INV2048 4.8828125e-4f

__global__ __launch_bounds__(64)
__attribute__((amdgpu_waves_per_eu(1, 1)))
void sig_pde(const float* __restrict__ X,
             const float* __restrict__ Y,
             float* __restrict__ partial) {
    const int bid = blockIdx.x;
    const int p = bid >> 8;          // 0=xx, 1=yy, 2=xy
    const int a = bid & 255;
    const float* __restrict__ U = (p == 1) ? Y : X;   // rows (i)
    const float* __restrict__ V = (p == 0) ? X : Y;   // cols (j)
    U += (size_t)a * 256 * 32;
    V += (size_t)a * 256 * 32;
    const int lane = threadIdx.x;
    const int m16 = lane & 15;           // row/col within MFMA tile
    const int g2 = (lane >> 4) * 2;      // k-group offset in float4 units

    __shared__ __attribute__((aligned(16))) u32x4 bH[16 * 64];   // 16 KB
    __shared__ __attribute__((aligned(16))) u32x4 bL[16 * 64];   // 16 KB
    __shared__ __attribute__((aligned(16))) float incL[16 * 260]; // 16.6 KB

    const float4* U4 = (const float4*)U;
    const float4* V4 = (const float4*)V;

    // ---- Stage B fragments: dY[n][k] hi/lo, frag layout n=lane&15,
    // k=(lane>>4)*8+i (the B^T-GEMM idiom). Col 255 clamps -> dY=0. ----
#pragma unroll
    for (int t = 0; t < 16; ++t) {
        int col = t * 16 + m16;
        int cp = (col + 1 < 256) ? col + 1 : 255;
        float4 lo0 = V4[col * 8 + g2], lo1 = V4[col * 8 + g2 + 1];
        float4 hi0 = V4[cp * 8 + g2],  hi1 = V4[cp * 8 + g2 + 1];
        float d[8] = {hi0.x - lo0.x, hi0.y - lo0.y, hi0.z - lo0.z, hi0.w - lo0.w,
                      hi1.x - lo1.x, hi1.y - lo1.y, hi1.z - lo1.z, hi1.w - lo1.w};
        half8 bh, bl;
#pragma unroll
        for (int i = 0; i < 8; ++i) {
            _Float16 h = (_Float16)d[i];
            bh[i] = h;
            bl[i] = (_Float16)((d[i] - (float)h) * 2048.0f);
        }
        bH[t * 64 + lane] = __builtin_bit_cast(u32x4, bh);
        bL[t * 64 + lane] = __builtin_bit_cast(u32x4, bl);
    }
    // single wave: DS ordering via lgkmcnt, no barrier needed

    // K row state: kp{0..3} = K[r][4*lane+s], row 0 = ones
    float kp0 = 1.0f, kp1 = 1.0f, kp2 = 1.0f, kp3 = 1.0f;

    // A-frag raw rows: lane reads U[16b+m16][g*8..+8) and the next row.
    auto loadA = [&](int blk, float4 (&dst)[4]) {
        int r0 = blk * 16 + m16;
        int r1 = (r0 + 1 < 256) ? r0 + 1 : 255;   // dX[255] := 0 (unscanned)
        dst[0] = U4[r0 * 8 + g2];
        dst[1] = U4[r0 * 8 + g2 + 1];
        dst[2] = U4[r1 * 8 + g2];
        dst[3] = U4[r1 * 8 + g2 + 1];
    };

    // One scan row: mv = inc[r][4l..4l+3] - 1 (the -1 is folded in MFMA)
    auto scan_row = [&](float4 mv) {
        float kn = __int_as_float(__builtin_amdgcn_update_dpp(
            0, __float_as_int(kp0), 0x130 /*wave_shl:1*/, 0xF, 0xF, true));
        float c0 = fmaf(kp0, mv.x, kp1);
        float c1 = fmaf(kp1, mv.y, kp2);
        float c2 = fmaf(kp2, mv.z, kp3);
        float c3 = (lane == 63) ? 0.0f : fmaf(kp3, mv.w, kn);
        float L0 = c0, L1 = L0 + c1, L2 = L1 + c2;
        float T = L2 + c3;
        float S = T;
        S = DPP_ADD(S, 0x111, 0xF);  // row_shr:1
        S = DPP_ADD(S, 0x112, 0xF);  // row_shr:2
        S = DPP_ADD(S, 0x114, 0xF);  // row_shr:4
        S = DPP_ADD(S, 0x118, 0xF);  // row_shr:8
        S = DPP_ADD(S, 0x142, 0xA);  // row_bcast:15 -> rows 1,3
        S = DPP_ADD(S, 0x143, 0xC);  // row_bcast:31 -> rows 2,3
        float E = S - T;
        kp0 = 1.0f + E;
        kp1 = 1.0f + E + L0;
        kp2 = 1.0f + E + L1;
        kp3 = 1.0f + E + L2;
    };

    // MFMA one 16-row block: 16 col-tiles x 3 mfma, combine, write inc-1.
    auto mfma_block = [&](const float4 (&src)[4]) {
        float d[8] = {src[2].x - src[0].x, src[2].y - src[0].y,
                      src[2].z - src[0].z, src[2].w - src[0].w,
                      src[3].x - src[1].x, src[3].y - src[1].y,
                      src[3].z - src[1].z, src[3].w - src[1].w};
        half8 ah, al;
#pragma unroll
        for (int i = 0; i < 8; ++i) {
            _Float16 h = (_Float16)d[i];
            ah[i] = h;
            al[i] = (_Float16)((d[i] - (float)h) * 2048.0f);
        }
        const f32x4_t zero4 = {0.0f, 0.0f, 0.0f, 0.0f};
        const f32x4_t mone4 = {-1.0f, -1.0f, -1.0f, -1.0f};
        const int rb = (lane >> 4) << 2;   // C rows g*4..g*4+3
#pragma unroll
        for (int t = 0; t < 16; ++t) {
            half8 bh = __builtin_bit_cast(half8, bH[t * 64 + lane]);
            half8 bl = __builtin_bit_cast(half8, bL[t * 64 + lane]);
            f32x4_t acc2 =
                __builtin_amdgcn_mfma_f32_16x16x32_f16(ah, bl, zero4, 0, 0, 0);
            acc2 = __builtin_amdgcn_mfma_f32_16x16x32_f16(al, bh, acc2, 0, 0, 0);
            f32x4_t acc1 =
                __builtin_amdgcn_mfma_f32_16x16x32_f16(ah, bh, mone4, 0, 0, 0);
            int cc = t * 16 + m16;
            incL[(rb + 0) * 260 + cc] = fmaf(acc2[0], INV2048, acc1[0]);
            incL[(rb + 1) * 260 + cc] = fmaf(acc2[1], INV2048, acc1[1]);
            incL[(rb + 2) * 260 + cc] = fmaf(acc2[2], INV2048, acc1[2]);
            incL[(rb + 3) * 260 + cc] = fmaf(acc2[3], INV2048, acc1[3]);
        }
    };

    auto scan_block = [&](int nrows) {
        const float4* rp = (const float4*)incL;   // 260 floats = 65 float4/row
        for (int r = 0; r < nrows; ++r) scan_row(rp[r * 65 + lane]);
    };

    // Iteration b: prefetch A(b+1) | scan block b-1 | MFMA+write block b.
    // Single inc buffer is safe: scan reads precede this block's writes.
    auto iteration = [&](float4 (&cur)[4], float4 (&nxt)[4], int b) {
        if (b + 1 < 16) loadA(b + 1, nxt);
        if (b > 0) scan_block((b == 16) ? 15 : 16);   // skip inc row 255
        if (b < 16) mfma_block(cur);
    };

    float4 bufE[4], bufO[4];
    loadA(0, bufE);
    for (int b = 0; b < 17; b += 2) {
        iteration(bufE, bufO, b);
        if (b + 1 < 17) iteration(bufO, bufE, b + 1);
    }

    if (lane == 63) {
        // kp3 = K[255][255]
        partial[bid] = (p == 2 ? -2.0f : 1.0f) * kp3;
    }
}

__global__ __launch_bounds__(256) void sig_reduce(const float* __restrict__ partial,
                                                  float* __restrict__ out) {
    const int t = threadIdx.x;
    float v = partial[t] + partial[t + 256] + partial[t + 512];
#pragma unroll
    for (int ofs = 32; ofs > 0; ofs >>= 1) v += __shfl_down(v, ofs);
    __shared__ float ws[4];
    if ((t & 63) == 0) ws[t >> 6] = v;
    __syncthreads();
    if (t == 0) out[0] = (ws[0] + ws[1] + ws[2] + ws[3]) * (1.0f / 256.0f);
}

extern "C" void kernel_launch(void* const* d_in, const int* in_sizes, int n_in,
                              void* d_out, int out_size, void* d_ws, size_t ws_size,
                              hipStream_t stream) {
    const float* X = (const float*)d_in[0];
    const float* Y = (const float*)d_in[1];
    float* partial = (float*)d_ws;       // 768 floats
    sig_pde<<<dim3(768), dim3(64), 0, stream>>>(X, Y, partial);
    sig_reduce<<<dim3(1), dim3(256), 0, stream>>>(partial, (float*)d_out);
}

// Round 12
// 50.440 us; speedup vs baseline: 2.8723x; 1.1346x over previous
//
#include <hip/hip_runtime.h>

// SigLoss: signature kernel PDE, loss = mean_a( K(X,X) + K(Y,Y) - 2 K(X,Y) ).
// A=256, L=256, D=32. One 64-lane wave per (pair,a) problem.
// R12 = R11 (MFMA inc via two-term f16 split, DPP scan; 57us) with the scan
// de-latencied: R11's scan_block was a RUNTIME loop -> per row ds_read_b128
// + ~120cyc wait + ~60cyc chain = ~190cyc/row serial (48k cyc total; VALU
// 22%, Mfma 6% -> 75% idle). Now: fully unrolled 16-row scan in 4-row groups,
// double-buffered named register prefetch (ga*/gb*, compile-time indices) so
// LDS latency hides under the previous group's scan chain; main loop is an
// explicit 2-step unroll so mfma_block(b) can interleave with scan(b-1)
// (independent; DS same-wave ordering keeps the single inc buffer race-free).

typedef _Float16 half8 __attribute__((ext_vector_type(8)));
typedef float f32x4_t __attribute__((ext_vector_type(4)));
typedef unsigned int u32x4 __attribute__((ext_vector_type(4)));

#define DPP_ADD(v, ctrl, rmask)                                               \
    ((v) + __int_as_float(__builtin_amdgcn_update_dpp(                        \
               0, __float_as_int(v), (ctrl), (rmask), 0xF, true)))

#define INV2048 4.8828125e-4f

__global__ __launch_bounds__(64)
__attribute__((amdgpu_waves_per_eu(1, 1)))
void sig_pde(const float* __restrict__ X,
             const float* __restrict__ Y,
             float* __restrict__ partial) {
    const int bid = blockIdx.x;
    const int p = bid >> 8;          // 0=xx, 1=yy, 2=xy
    const int a = bid & 255;
    const float* __restrict__ U = (p == 1) ? Y : X;   // rows (i)
    const float* __restrict__ V = (p == 0) ? X : Y;   // cols (j)
    U += (size_t)a * 256 * 32;
    V += (size_t)a * 256 * 32;
    const int lane = threadIdx.x;
    const int m16 = lane & 15;           // row/col within MFMA tile
    const int g2 = (lane >> 4) * 2;      // k-group offset in float4 units

    __shared__ __attribute__((aligned(16))) u32x4 bH[16 * 64];   // 16 KB
    __shared__ __attribute__((aligned(16))) u32x4 bL[16 * 64];   // 16 KB
    __shared__ __attribute__((aligned(16))) float incL[16 * 260]; // 16.6 KB

    const float4* U4 = (const float4*)U;
    const float4* V4 = (const float4*)V;

    // ---- Stage B fragments: dY[n][k] hi/lo, frag layout n=lane&15,
    // k=(lane>>4)*8+i (B^T-GEMM idiom). Col 255 clamps -> dY=0. ----
#pragma unroll
    for (int t = 0; t < 16; ++t) {
        int col = t * 16 + m16;
        int cp = (col + 1 < 256) ? col + 1 : 255;
        float4 lo0 = V4[col * 8 + g2], lo1 = V4[col * 8 + g2 + 1];
        float4 hi0 = V4[cp * 8 + g2],  hi1 = V4[cp * 8 + g2 + 1];
        float d[8] = {hi0.x - lo0.x, hi0.y - lo0.y, hi0.z - lo0.z, hi0.w - lo0.w,
                      hi1.x - lo1.x, hi1.y - lo1.y, hi1.z - lo1.z, hi1.w - lo1.w};
        half8 bh, bl;
#pragma unroll
        for (int i = 0; i < 8; ++i) {
            _Float16 h = (_Float16)d[i];
            bh[i] = h;
            bl[i] = (_Float16)((d[i] - (float)h) * 2048.0f);
        }
        bH[t * 64 + lane] = __builtin_bit_cast(u32x4, bh);
        bL[t * 64 + lane] = __builtin_bit_cast(u32x4, bl);
    }
    // single wave: same-wave DS ordering, no barrier needed

    // K row state: kp{0..3} = K[r][4*lane+s], row 0 = ones
    float kp0 = 1.0f, kp1 = 1.0f, kp2 = 1.0f, kp3 = 1.0f;

    // A-frag raw rows: lane reads U[16b+m16][g*8..+8) and the next row.
    auto loadA = [&](int blk, float4 (&dst)[4]) {
        int r0 = blk * 16 + m16;
        int r1 = (r0 + 1 < 256) ? r0 + 1 : 255;   // dX[255] := 0 (unscanned)
        dst[0] = U4[r0 * 8 + g2];
        dst[1] = U4[r0 * 8 + g2 + 1];
        dst[2] = U4[r1 * 8 + g2];
        dst[3] = U4[r1 * 8 + g2 + 1];
    };

    // One scan row: mv = inc[r][4l..4l+3] - 1 (the -1 folded into MFMA)
    auto scan_row = [&](float4 mv) {
        float kn = __int_as_float(__builtin_amdgcn_update_dpp(
            0, __float_as_int(kp0), 0x130 /*wave_shl:1*/, 0xF, 0xF, true));
        float c0 = fmaf(kp0, mv.x, kp1);
        float c1 = fmaf(kp1, mv.y, kp2);
        float c2 = fmaf(kp2, mv.z, kp3);
        float c3 = (lane == 63) ? 0.0f : fmaf(kp3, mv.w, kn);
        float L0 = c0, L1 = L0 + c1, L2 = L1 + c2;
        float T = L2 + c3;
        float S = T;
        S = DPP_ADD(S, 0x111, 0xF);  // row_shr:1
        S = DPP_ADD(S, 0x112, 0xF);  // row_shr:2
        S = DPP_ADD(S, 0x114, 0xF);  // row_shr:4
        S = DPP_ADD(S, 0x118, 0xF);  // row_shr:8
        S = DPP_ADD(S, 0x142, 0xA);  // row_bcast:15 -> rows 1,3
        S = DPP_ADD(S, 0x143, 0xC);  // row_bcast:31 -> rows 2,3
        float E = S - T;
        kp0 = 1.0f + E;
        kp1 = 1.0f + E + L0;
        kp2 = 1.0f + E + L1;
        kp3 = 1.0f + E + L2;
    };

    // Unrolled 16-row scan: 4-row groups, double-buffered register prefetch.
    // All reg names static (rule: no runtime-indexed arrays -> no scratch).
    const float4* rp = (const float4*)incL;   // 65 float4 per row
#define RD(Gv, r) Gv = rp[(r) * 65 + lane]
    auto scan16 = [&](bool full) {
        float4 ga0, ga1, ga2, ga3, gb0, gb1, gb2, gb3;
        RD(ga0, 0); RD(ga1, 1); RD(ga2, 2); RD(ga3, 3);
        RD(gb0, 4); RD(gb1, 5); RD(gb2, 6); RD(gb3, 7);
        scan_row(ga0); scan_row(ga1); scan_row(ga2); scan_row(ga3);
        RD(ga0, 8); RD(ga1, 9); RD(ga2, 10); RD(ga3, 11);
        scan_row(gb0); scan_row(gb1); scan_row(gb2); scan_row(gb3);
        RD(gb0, 12); RD(gb1, 13); RD(gb2, 14);
        if (full) RD(gb3, 15);
        scan_row(ga0); scan_row(ga1); scan_row(ga2); scan_row(ga3);
        scan_row(gb0); scan_row(gb1); scan_row(gb2);
        if (full) scan_row(gb3);
    };
#undef RD

    // MFMA one 16-row block: 16 col-tiles x 3 mfma, combine, write inc-1.
    auto mfma_block = [&](const float4 (&src)[4]) {
        float d[8] = {src[2].x - src[0].x, src[2].y - src[0].y,
                      src[2].z - src[0].z, src[2].w - src[0].w,
                      src[3].x - src[1].x, src[3].y - src[1].y,
                      src[3].z - src[1].z, src[3].w - src[1].w};
        half8 ah, al;
#pragma unroll
        for (int i = 0; i < 8; ++i) {
            _Float16 h = (_Float16)d[i];
            ah[i] = h;
            al[i] = (_Float16)((d[i] - (float)h) * 2048.0f);
        }
        const f32x4_t zero4 = {0.0f, 0.0f, 0.0f, 0.0f};
        const f32x4_t mone4 = {-1.0f, -1.0f, -1.0f, -1.0f};
        const int rb = (lane >> 4) << 2;   // C rows g*4..g*4+3
#pragma unroll
        for (int t = 0; t < 16; ++t) {
            half8 bh = __builtin_bit_cast(half8, bH[t * 64 + lane]);
            half8 bl = __builtin_bit_cast(half8, bL[t * 64 + lane]);
            f32x4_t acc2 =
                __builtin_amdgcn_mfma_f32_16x16x32_f16(ah, bl, zero4, 0, 0, 0);
            acc2 = __builtin_amdgcn_mfma_f32_16x16x32_f16(al, bh, acc2, 0, 0, 0);
            f32x4_t acc1 =
                __builtin_amdgcn_mfma_f32_16x16x32_f16(ah, bh, mone4, 0, 0, 0);
            int cc = t * 16 + m16;
            incL[(rb + 0) * 260 + cc] = fmaf(acc2[0], INV2048, acc1[0]);
            incL[(rb + 1) * 260 + cc] = fmaf(acc2[1], INV2048, acc1[1]);
            incL[(rb + 2) * 260 + cc] = fmaf(acc2[2], INV2048, acc1[2]);
            incL[(rb + 3) * 260 + cc] = fmaf(acc2[3], INV2048, acc1[3]);
        }
    };

    // Main pipeline: mfma(0); then { loadA(b) | scan(b-1) | mfma(b) } with an
    // explicit 2-step unroll (no runtime-parity register selection).
    float4 A0[4], A1[4];
    loadA(0, A0);
    mfma_block(A0);
    int b = 1;
    for (; b + 1 < 16; b += 2) {         // b = 1,3,...,13
        loadA(b, A1);
        scan16(true);                    // block b-1
        mfma_block(A1);
        loadA(b + 1, A0);
        scan16(true);                    // block b
        mfma_block(A0);
    }
    loadA(15, A1);
    scan16(true);                        // block 14
    mfma_block(A1);
    scan16(false);                       // block 15: 15 rows (inc row 255 n/a)

    if (lane == 63) {
        // kp3 = K[255][255]
        partial[bid] = (p == 2 ? -2.0f : 1.0f) * kp3;
    }
}

__global__ __launch_bounds__(256) void sig_reduce(const float* __restrict__ partial,
                                                  float* __restrict__ out) {
    const int t = threadIdx.x;
    float v = partial[t] + partial[t + 256] + partial[t + 512];
#pragma unroll
    for (int ofs = 32; ofs > 0; ofs >>= 1) v += __shfl_down(v, ofs);
    __shared__ float ws[4];
    if ((t & 63) == 0) ws[t >> 6] = v;
    __syncthreads();
    if (t == 0) out[0] = (ws[0] + ws[1] + ws[2] + ws[3]) * (1.0f / 256.0f);
}

extern "C" void kernel_launch(void* const* d_in, const int* in_sizes, int n_in,
                              void* d_out, int out_size, void* d_ws, size_t ws_size,
                              hipStream_t stream) {
    const float* X = (const float*)d_in[0];
    const float* Y = (const float*)d_in[1];
    float* partial = (float*)d_ws;       // 768 floats
    sig_pde<<<dim3(768), dim3(64), 0, stream>>>(X, Y, partial);
    sig_reduce<<<dim3(1), dim3(256), 0, stream>>>(partial, (float*)d_out);
}

// Round 13
// 44.304 us; speedup vs baseline: 3.2701x; 1.1385x over previous
//
#include <hip/hip_runtime.h>

// SigLoss: signature kernel PDE, loss = mean_a( K(X,X) + K(Y,Y) - 2 K(X,Y) ).
// A=256, L=256, D=32. One 64-lane wave per (pair,a) problem.
// R13 = R12 minus register spills. R12 hit the 256-VGPR hard cap and spilled
// ~5KB/wave to scratch (WRITE_SIZE 24KB -> 3.9MB): the 2-step-unrolled main
// loop overlapped two scan16+mfma_block lifetimes, and the fully-unrolled
// B-staging issued 64 float4 loads at once. Fix: single A buffer + rolled
// main loop (loadA(b) issues right before scan16(b-1), which hides it), and
// stage loop unroll(2). Scan keeps the 4-row double-buffered prefetch.

typedef _Float16 half8 __attribute__((ext_vector_type(8)));
typedef float f32x4_t __attribute__((ext_vector_type(4)));
typedef unsigned int u32x4 __attribute__((ext_vector_type(4)));

#define DPP_ADD(v, ctrl, rmask)                                               \
    ((v) + __int_as_float(__builtin_amdgcn_update_dpp(                        \
               0, __float_as_int(v), (ctrl), (rmask), 0xF, true)))

#define INV2048 4.8828125e-4f

__global__ __launch_bounds__(64)
__attribute__((amdgpu_waves_per_eu(1, 1)))
void sig_pde(const float* __restrict__ X,
             const float* __restrict__ Y,
             float* __restrict__ partial) {
    const int bid = blockIdx.x;
    const int p = bid >> 8;          // 0=xx, 1=yy, 2=xy
    const int a = bid & 255;
    const float* __restrict__ U = (p == 1) ? Y : X;   // rows (i)
    const float* __restrict__ V = (p == 0) ? X : Y;   // cols (j)
    U += (size_t)a * 256 * 32;
    V += (size_t)a * 256 * 32;
    const int lane = threadIdx.x;
    const int m16 = lane & 15;           // row/col within MFMA tile
    const int g2 = (lane >> 4) * 2;      // k-group offset in float4 units

    __shared__ __attribute__((aligned(16))) u32x4 bH[16 * 64];   // 16 KB
    __shared__ __attribute__((aligned(16))) u32x4 bL[16 * 64];   // 16 KB
    __shared__ __attribute__((aligned(16))) float incL[16 * 260]; // 16.6 KB

    const float4* U4 = (const float4*)U;
    const float4* V4 = (const float4*)V;

    // ---- Stage B fragments: dY[n][k] hi/lo, frag layout n=lane&15,
    // k=(lane>>4)*8+i (B^T-GEMM idiom). Col 255 clamps -> dY=0. ----
#pragma unroll 2
    for (int t = 0; t < 16; ++t) {
        int col = t * 16 + m16;
        int cp = (col + 1 < 256) ? col + 1 : 255;
        float4 lo0 = V4[col * 8 + g2], lo1 = V4[col * 8 + g2 + 1];
        float4 hi0 = V4[cp * 8 + g2],  hi1 = V4[cp * 8 + g2 + 1];
        float d[8] = {hi0.x - lo0.x, hi0.y - lo0.y, hi0.z - lo0.z, hi0.w - lo0.w,
                      hi1.x - lo1.x, hi1.y - lo1.y, hi1.z - lo1.z, hi1.w - lo1.w};
        half8 bh, bl;
#pragma unroll
        for (int i = 0; i < 8; ++i) {
            _Float16 h = (_Float16)d[i];
            bh[i] = h;
            bl[i] = (_Float16)((d[i] - (float)h) * 2048.0f);
        }
        bH[t * 64 + lane] = __builtin_bit_cast(u32x4, bh);
        bL[t * 64 + lane] = __builtin_bit_cast(u32x4, bl);
    }
    // single wave: same-wave DS ordering, no barrier needed

    // K row state: kp{0..3} = K[r][4*lane+s], row 0 = ones
    float kp0 = 1.0f, kp1 = 1.0f, kp2 = 1.0f, kp3 = 1.0f;

    // A-frag raw rows: lane reads U[16b+m16][g*8..+8) and the next row.
    auto loadA = [&](int blk, float4 (&dst)[4]) {
        int r0 = blk * 16 + m16;
        int r1 = (r0 + 1 < 256) ? r0 + 1 : 255;   // dX[255] := 0 (unscanned)
        dst[0] = U4[r0 * 8 + g2];
        dst[1] = U4[r0 * 8 + g2 + 1];
        dst[2] = U4[r1 * 8 + g2];
        dst[3] = U4[r1 * 8 + g2 + 1];
    };

    // One scan row: mv = inc[r][4l..4l+3] - 1 (the -1 folded into MFMA)
    auto scan_row = [&](float4 mv) {
        float kn = __int_as_float(__builtin_amdgcn_update_dpp(
            0, __float_as_int(kp0), 0x130 /*wave_shl:1*/, 0xF, 0xF, true));
        float c0 = fmaf(kp0, mv.x, kp1);
        float c1 = fmaf(kp1, mv.y, kp2);
        float c2 = fmaf(kp2, mv.z, kp3);
        float c3 = (lane == 63) ? 0.0f : fmaf(kp3, mv.w, kn);
        float L0 = c0, L1 = L0 + c1, L2 = L1 + c2;
        float T = L2 + c3;
        float S = T;
        S = DPP_ADD(S, 0x111, 0xF);  // row_shr:1
        S = DPP_ADD(S, 0x112, 0xF);  // row_shr:2
        S = DPP_ADD(S, 0x114, 0xF);  // row_shr:4
        S = DPP_ADD(S, 0x118, 0xF);  // row_shr:8
        S = DPP_ADD(S, 0x142, 0xA);  // row_bcast:15 -> rows 1,3
        S = DPP_ADD(S, 0x143, 0xC);  // row_bcast:31 -> rows 2,3
        float E = S - T;
        kp0 = 1.0f + E;
        kp1 = 1.0f + E + L0;
        kp2 = 1.0f + E + L1;
        kp3 = 1.0f + E + L2;
    };

    // Unrolled 16-row scan: 4-row groups, double-buffered register prefetch.
    const float4* rp = (const float4*)incL;   // 65 float4 per row
#define RD(Gv, r) Gv = rp[(r) * 65 + lane]
    auto scan16 = [&](bool full) {
        float4 ga0, ga1, ga2, ga3, gb0, gb1, gb2, gb3;
        RD(ga0, 0); RD(ga1, 1); RD(ga2, 2); RD(ga3, 3);
        RD(gb0, 4); RD(gb1, 5); RD(gb2, 6); RD(gb3, 7);
        scan_row(ga0); scan_row(ga1); scan_row(ga2); scan_row(ga3);
        RD(ga0, 8); RD(ga1, 9); RD(ga2, 10); RD(ga3, 11);
        scan_row(gb0); scan_row(gb1); scan_row(gb2); scan_row(gb3);
        RD(gb0, 12); RD(gb1, 13); RD(gb2, 14);
        if (full) RD(gb3, 15);
        scan_row(ga0); scan_row(ga1); scan_row(ga2); scan_row(ga3);
        scan_row(gb0); scan_row(gb1); scan_row(gb2);
        if (full) scan_row(gb3);
    };
#undef RD

    // MFMA one 16-row block: 16 col-tiles x 3 mfma, combine, write inc-1.
    auto mfma_block = [&](const float4 (&src)[4]) {
        float d[8] = {src[2].x - src[0].x, src[2].y - src[0].y,
                      src[2].z - src[0].z, src[2].w - src[0].w,
                      src[3].x - src[1].x, src[3].y - src[1].y,
                      src[3].z - src[1].z, src[3].w - src[1].w};
        half8 ah, al;
#pragma unroll
        for (int i = 0; i < 8; ++i) {
            _Float16 h = (_Float16)d[i];
            ah[i] = h;
            al[i] = (_Float16)((d[i] - (float)h) * 2048.0f);
        }
        const f32x4_t zero4 = {0.0f, 0.0f, 0.0f, 0.0f};
        const f32x4_t mone4 = {-1.0f, -1.0f, -1.0f, -1.0f};
        const int rb = (lane >> 4) << 2;   // C rows g*4..g*4+3
#pragma unroll
        for (int t = 0; t < 16; ++t) {
            half8 bh = __builtin_bit_cast(half8, bH[t * 64 + lane]);
            half8 bl = __builtin_bit_cast(half8, bL[t * 64 + lane]);
            f32x4_t acc2 =
                __builtin_amdgcn_mfma_f32_16x16x32_f16(ah, bl, zero4, 0, 0, 0);
            acc2 = __builtin_amdgcn_mfma_f32_16x16x32_f16(al, bh, acc2, 0, 0, 0);
            f32x4_t acc1 =
                __builtin_amdgcn_mfma_f32_16x16x32_f16(ah, bh, mone4, 0, 0, 0);
            int cc = t * 16 + m16;
            incL[(rb + 0) * 260 + cc] = fmaf(acc2[0], INV2048, acc1[0]);
            incL[(rb + 1) * 260 + cc] = fmaf(acc2[1], INV2048, acc1[1]);
            incL[(rb + 2) * 260 + cc] = fmaf(acc2[2], INV2048, acc1[2]);
            incL[(rb + 3) * 260 + cc] = fmaf(acc2[3], INV2048, acc1[3]);
        }
    };

    // Main pipeline, rolled, single A buffer:
    //   mfma(0); for b=1..15 { loadA(b) | scan16(b-1) | mfma(b) }; scan16(15)
    float4 A[4];
    loadA(0, A);
    mfma_block(A);
#pragma clang loop unroll(disable)
    for (int b = 1; b < 16; ++b) {
        loadA(b, A);                 // issue global loads; hidden under scan
        scan16(true);                // scan block b-1
        mfma_block(A);               // compute + write block b
    }
    scan16(false);                   // block 15: 15 rows (inc row 255 n/a)

    if (lane == 63) {
        // kp3 = K[255][255]
        partial[bid] = (p == 2 ? -2.0f : 1.0f) * kp3;
    }
}

__global__ __launch_bounds__(256) void sig_reduce(const float* __restrict__ partial,
                                                  float* __restrict__ out) {
    const int t = threadIdx.x;
    float v = partial[t] + partial[t + 256] + partial[t + 512];
#pragma unroll
    for (int ofs = 32; ofs > 0; ofs >>= 1) v += __shfl_down(v, ofs);
    __shared__ float ws[4];
    if ((t & 63) == 0) ws[t >> 6] = v;
    __syncthreads();
    if (t == 0) out[0] = (ws[0] + ws[1] + ws[2] + ws[3]) * (1.0f / 256.0f);
}

extern "C" void kernel_launch(void* const* d_in, const int* in_sizes, int n_in,
                              void* d_out, int out_size, void* d_ws, size_t ws_size,
                              hipStream_t stream) {
    const float* X = (const float*)d_in[0];
    const float* Y = (const float*)d_in[1];
    float* partial = (float*)d_ws;       // 768 floats
    sig_pde<<<dim3(768), dim3(64), 0, stream>>>(X, Y, partial);
    sig_reduce<<<dim3(1), dim3(256), 0, stream>>>(partial, (float*)d_out);
}

// Round 14
// 43.619 us; speedup vs baseline: 3.3214x; 1.0157x over previous
//
#include <hip/hip_runtime.h>

// SigLoss: signature kernel PDE, loss = mean_a( K(X,X) + K(Y,Y) - 2 K(X,Y) ).
// A=256, L=256, D=32. One 64-lane wave per (pair,a) problem.
// R14 = R13 with scan/MFMA manually interleaved. R13 (44us, VALU 28%, Mfma 8%)
// serialized scan16(b-1) then mfma_block(b); the single incL buffer's
// may-alias ordering pinned that. Now: issue ALL 16 inc-row ds_reads upfront
// (program order before block b's writes -> same-wave in-order DS returns old
// data, the idiom R11-R13 validated), then alternate {scan 4 rows, reg-only}
// with {4 MFMA tiles + combine + writes}. Scan-chain stalls fill with MFMA
// issue and vice versa. Reg audit: 16 row-float4 (64) + A (16) + transients
// ~= 170-190 < R13's 192 grant -> no spill.

typedef _Float16 half8 __attribute__((ext_vector_type(8)));
typedef float f32x4_t __attribute__((ext_vector_type(4)));
typedef unsigned int u32x4 __attribute__((ext_vector_type(4)));

#define DPP_ADD(v, ctrl, rmask)                                               \
    ((v) + __int_as_float(__builtin_amdgcn_update_dpp(                        \
               0, __float_as_int(v), (ctrl), (rmask), 0xF, true)))

#define INV2048 4.8828125e-4f

__global__ __launch_bounds__(64)
__attribute__((amdgpu_waves_per_eu(1, 1)))
void sig_pde(const float* __restrict__ X,
             const float* __restrict__ Y,
             float* __restrict__ partial) {
    const int bid = blockIdx.x;
    const int p = bid >> 8;          // 0=xx, 1=yy, 2=xy
    const int a = bid & 255;
    const float* __restrict__ U = (p == 1) ? Y : X;   // rows (i)
    const float* __restrict__ V = (p == 0) ? X : Y;   // cols (j)
    U += (size_t)a * 256 * 32;
    V += (size_t)a * 256 * 32;
    const int lane = threadIdx.x;
    const int m16 = lane & 15;           // row/col within MFMA tile
    const int g2 = (lane >> 4) * 2;      // k-group offset in float4 units

    __shared__ __attribute__((aligned(16))) u32x4 bH[16 * 64];   // 16 KB
    __shared__ __attribute__((aligned(16))) u32x4 bL[16 * 64];   // 16 KB
    __shared__ __attribute__((aligned(16))) float incL[16 * 260]; // 16.6 KB

    const float4* U4 = (const float4*)U;
    const float4* V4 = (const float4*)V;

    // ---- Stage B fragments: dY[n][k] hi/lo, frag layout n=lane&15,
    // k=(lane>>4)*8+i (B^T-GEMM idiom). Col 255 clamps -> dY=0. ----
#pragma unroll 2
    for (int t = 0; t < 16; ++t) {
        int col = t * 16 + m16;
        int cp = (col + 1 < 256) ? col + 1 : 255;
        float4 lo0 = V4[col * 8 + g2], lo1 = V4[col * 8 + g2 + 1];
        float4 hi0 = V4[cp * 8 + g2],  hi1 = V4[cp * 8 + g2 + 1];
        float d[8] = {hi0.x - lo0.x, hi0.y - lo0.y, hi0.z - lo0.z, hi0.w - lo0.w,
                      hi1.x - lo1.x, hi1.y - lo1.y, hi1.z - lo1.z, hi1.w - lo1.w};
        half8 bh, bl;
#pragma unroll
        for (int i = 0; i < 8; ++i) {
            _Float16 h = (_Float16)d[i];
            bh[i] = h;
            bl[i] = (_Float16)((d[i] - (float)h) * 2048.0f);
        }
        bH[t * 64 + lane] = __builtin_bit_cast(u32x4, bh);
        bL[t * 64 + lane] = __builtin_bit_cast(u32x4, bl);
    }
    // single wave: same-wave DS ordering, no barrier needed

    // K row state: kp{0..3} = K[r][4*lane+s], row 0 = ones
    float kp0 = 1.0f, kp1 = 1.0f, kp2 = 1.0f, kp3 = 1.0f;

    // A-frag raw rows: lane reads U[16b+m16][g*8..+8) and the next row.
    auto loadA = [&](int blk, float4 (&dst)[4]) {
        int r0 = blk * 16 + m16;
        int r1 = (r0 + 1 < 256) ? r0 + 1 : 255;   // dX[255] := 0 (unscanned)
        dst[0] = U4[r0 * 8 + g2];
        dst[1] = U4[r0 * 8 + g2 + 1];
        dst[2] = U4[r1 * 8 + g2];
        dst[3] = U4[r1 * 8 + g2 + 1];
    };

    // dX block -> two-term f16 split fragments
    auto makeAhAl = [&](const float4 (&src)[4], half8& ah, half8& al) {
        float d[8] = {src[2].x - src[0].x, src[2].y - src[0].y,
                      src[2].z - src[0].z, src[2].w - src[0].w,
                      src[3].x - src[1].x, src[3].y - src[1].y,
                      src[3].z - src[1].z, src[3].w - src[1].w};
#pragma unroll
        for (int i = 0; i < 8; ++i) {
            _Float16 h = (_Float16)d[i];
            ah[i] = h;
            al[i] = (_Float16)((d[i] - (float)h) * 2048.0f);
        }
    };

    // One scan row: mv = inc[r][4l..4l+3] - 1 (the -1 folded into MFMA)
    auto scan_row = [&](float4 mv) {
        float kn = __int_as_float(__builtin_amdgcn_update_dpp(
            0, __float_as_int(kp0), 0x130 /*wave_shl:1*/, 0xF, 0xF, true));
        float c0 = fmaf(kp0, mv.x, kp1);
        float c1 = fmaf(kp1, mv.y, kp2);
        float c2 = fmaf(kp2, mv.z, kp3);
        float c3 = (lane == 63) ? 0.0f : fmaf(kp3, mv.w, kn);
        float L0 = c0, L1 = L0 + c1, L2 = L1 + c2;
        float T = L2 + c3;
        float S = T;
        S = DPP_ADD(S, 0x111, 0xF);  // row_shr:1
        S = DPP_ADD(S, 0x112, 0xF);  // row_shr:2
        S = DPP_ADD(S, 0x114, 0xF);  // row_shr:4
        S = DPP_ADD(S, 0x118, 0xF);  // row_shr:8
        S = DPP_ADD(S, 0x142, 0xA);  // row_bcast:15 -> rows 1,3
        S = DPP_ADD(S, 0x143, 0xC);  // row_bcast:31 -> rows 2,3
        float E = S - T;
        kp0 = 1.0f + E;
        kp1 = 1.0f + E + L0;
        kp2 = 1.0f + E + L1;
        kp3 = 1.0f + E + L2;
    };

    const f32x4_t zero4 = {0.0f, 0.0f, 0.0f, 0.0f};
    const f32x4_t mone4 = {-1.0f, -1.0f, -1.0f, -1.0f};
    const int rb = (lane >> 4) << 2;     // C rows g*4..g*4+3

    // One MFMA col-tile: 3 mfma + combine + 4 inc writes
    auto mfma_tile = [&](int t, const half8& ah, const half8& al) {
        half8 bh = __builtin_bit_cast(half8, bH[t * 64 + lane]);
        half8 bl = __builtin_bit_cast(half8, bL[t * 64 + lane]);
        f32x4_t acc2 =
            __builtin_amdgcn_mfma_f32_16x16x32_f16(ah, bl, zero4, 0, 0, 0);
        acc2 = __builtin_amdgcn_mfma_f32_16x16x32_f16(al, bh, acc2, 0, 0, 0);
        f32x4_t acc1 =
            __builtin_amdgcn_mfma_f32_16x16x32_f16(ah, bh, mone4, 0, 0, 0);
        int cc = t * 16 + m16;
        incL[(rb + 0) * 260 + cc] = fmaf(acc2[0], INV2048, acc1[0]);
        incL[(rb + 1) * 260 + cc] = fmaf(acc2[1], INV2048, acc1[1]);
        incL[(rb + 2) * 260 + cc] = fmaf(acc2[2], INV2048, acc1[2]);
        incL[(rb + 3) * 260 + cc] = fmaf(acc2[3], INV2048, acc1[3]);
    };

    const float4* rp = (const float4*)incL;   // 65 float4 per row

    // ---- Block 0 (no scan yet) ----
    float4 A[4];
    loadA(0, A);
    {
        half8 ah, al;
        makeAhAl(A, ah, al);
#pragma unroll
        for (int t = 0; t < 16; ++t) mfma_tile(t, ah, al);
    }

    // ---- Iterations b = 1..15: read16(b-1) | interleave scan/mfma(b) ----
#define RD(n) float4 w##n = rp[(n) * 65 + lane]
#pragma clang loop unroll(disable)
    for (int b = 1; b < 16; ++b) {
        loadA(b, A);                 // global loads; hidden under reads+scan
        // Issue ALL reads of block b-1 before any write of block b
        RD(0); RD(1); RD(2); RD(3); RD(4); RD(5); RD(6); RD(7);
        RD(8); RD(9); RD(10); RD(11); RD(12); RD(13); RD(14); RD(15);
        half8 ah, al;
        makeAhAl(A, ah, al);
        scan_row(w0); scan_row(w1); scan_row(w2); scan_row(w3);
        mfma_tile(0, ah, al); mfma_tile(1, ah, al);
        mfma_tile(2, ah, al); mfma_tile(3, ah, al);
        scan_row(w4); scan_row(w5); scan_row(w6); scan_row(w7);
        mfma_tile(4, ah, al); mfma_tile(5, ah, al);
        mfma_tile(6, ah, al); mfma_tile(7, ah, al);
        scan_row(w8); scan_row(w9); scan_row(w10); scan_row(w11);
        mfma_tile(8, ah, al); mfma_tile(9, ah, al);
        mfma_tile(10, ah, al); mfma_tile(11, ah, al);
        scan_row(w12); scan_row(w13); scan_row(w14); scan_row(w15);
        mfma_tile(12, ah, al); mfma_tile(13, ah, al);
        mfma_tile(14, ah, al); mfma_tile(15, ah, al);
    }

    // ---- Tail: scan block 15 (15 rows; inc row 255 doesn't exist) ----
    {
        RD(0); RD(1); RD(2); RD(3); RD(4); RD(5); RD(6); RD(7);
        RD(8); RD(9); RD(10); RD(11); RD(12); RD(13); RD(14);
        scan_row(w0); scan_row(w1); scan_row(w2); scan_row(w3);
        scan_row(w4); scan_row(w5); scan_row(w6); scan_row(w7);
        scan_row(w8); scan_row(w9); scan_row(w10); scan_row(w11);
        scan_row(w12); scan_row(w13); scan_row(w14);
    }
#undef RD

    if (lane == 63) {
        // kp3 = K[255][255]
        partial[bid] = (p == 2 ? -2.0f : 1.0f) * kp3;
    }
}

__global__ __launch_bounds__(256) void sig_reduce(const float* __restrict__ partial,
                                                  float* __restrict__ out) {
    const int t = threadIdx.x;
    float v = partial[t] + partial[t + 256] + partial[t + 512];
#pragma unroll
    for (int ofs = 32; ofs > 0; ofs >>= 1) v += __shfl_down(v, ofs);
    __shared__ float ws[4];
    if ((t & 63) == 0) ws[t >> 6] = v;
    __syncthreads();
    if (t == 0) out[0] = (ws[0] + ws[1] + ws[2] + ws[3]) * (1.0f / 256.0f);
}

extern "C" void kernel_launch(void* const* d_in, const int* in_sizes, int n_in,
                              void* d_out, int out_size, void* d_ws, size_t ws_size,
                              hipStream_t stream) {
    const float* X = (const float*)d_in[0];
    const float* Y = (const float*)d_in[1];
    float* partial = (float*)d_ws;       // 768 floats
    sig_pde<<<dim3(768), dim3(64), 0, stream>>>(X, Y, partial);
    sig_reduce<<<dim3(1), dim3(256), 0, stream>>>(partial, (float*)d_out);
}